// Round 5
// baseline (263.536 us; speedup 1.0000x reference)
//
#include <hip/hip_runtime.h>
#include <hip/hip_bf16.h>
#include <cstdint>

// Problem constants
#define Bb  8
#define Tt  2048
#define Cc  256
#define FDd 256
#define Kk  128
#define Vv  256
#define BT  (Bb * Tt)
#define NTRI 136          // 16*17/2 lower-triangular 128x128 blocks per batch

#define INV_SQRT_K 0.08838834764831845f  // 1/sqrt(128)

typedef __bf16 bf16x8 __attribute__((ext_vector_type(8)));
typedef __bf16 bf16x4 __attribute__((ext_vector_type(4)));
typedef float  f32x4  __attribute__((ext_vector_type(4)));

// ---------------------------------------------------------------------------
// prep: out[:, :256] = inp (fp32 copy) + bf16 conversions of inp and feature.
// ---------------------------------------------------------------------------
__global__ __launch_bounds__(256) void prep_kernel(
    const float4* __restrict__ inp4, const float4* __restrict__ feat4,
    float4* __restrict__ out4, bf16x4* __restrict__ inpB4,
    bf16x4* __restrict__ featB4)
{
  const int g = blockIdx.x * 256 + threadIdx.x;   // 0 .. BT*64
  const int row = g >> 6, c = g & 63;
  const float4 x = inp4[g];
  out4[(size_t)row * 128 + c] = x;
  bf16x4 xb; xb[0] = (__bf16)x.x; xb[1] = (__bf16)x.y; xb[2] = (__bf16)x.z; xb[3] = (__bf16)x.w;
  inpB4[g] = xb;
  const float4 f = feat4[g];
  bf16x4 fb; fb[0] = (__bf16)f.x; fb[1] = (__bf16)f.y; fb[2] = (__bf16)f.z; fb[3] = (__bf16)f.w;
  featB4[g] = fb;
}

// ---------------------------------------------------------------------------
// wprep: transpose + bf16-convert weights.
// ---------------------------------------------------------------------------
__global__ __launch_bounds__(256) void wprep_kernel(
    const float* __restrict__ Wq, const float* __restrict__ Wk,
    const float* __restrict__ Wv, __bf16* __restrict__ Wqt,
    __bf16* __restrict__ Wkt, __bf16* __restrict__ Wvt)
{
  const int g = blockIdx.x * 256 + threadIdx.x;
  if (g < 65536) {                       // Wq: 512x128 -> Wqt 128x512
    const int n = g >> 9, k = g & 511;
    Wqt[g] = (__bf16)Wq[k * 128 + n];
  } else if (g < 98304) {                // Wk: 256x128 -> Wkt 128x256
    const int h = g - 65536;
    const int n = h >> 8, k = h & 255;
    Wkt[h] = (__bf16)Wk[k * 128 + n];
  } else {                               // Wv: 256x256 -> Wvt 256x256
    const int h = g - 98304;
    const int n = h >> 8, k = h & 255;
    Wvt[h] = (__bf16)Wv[k * 256 + n];
  }
}

// ---------------------------------------------------------------------------
// qkv via MFMA. grid (BT/64, 4), block 256 (4 waves x 16 rows). (unchanged)
// ---------------------------------------------------------------------------
__global__ __launch_bounds__(256) void qkv_mfma_kernel(
    const __bf16* __restrict__ inpB, const __bf16* __restrict__ featB,
    const __bf16* __restrict__ Wqt, const __bf16* __restrict__ Wkt,
    const __bf16* __restrict__ Wvt,
    const float* __restrict__ bq, const float* __restrict__ bk,
    const float* __restrict__ bv,
    __bf16* __restrict__ qb, __bf16* __restrict__ kb, __bf16* __restrict__ vT)
{
  const int panel = blockIdx.y;
  const int lane = threadIdx.x & 63, wave = threadIdx.x >> 6;
  const int cl = lane & 15, quad = lane >> 4;
  const int row0 = blockIdx.x * 64 + wave * 16;

  const __bf16* Wt; const float* bias; int Kd;
  if (panel == 0)      { Wt = Wqt; bias = bq; Kd = 512; }
  else if (panel == 1) { Wt = Wkt; bias = bk; Kd = 256; }
  else                 { Wt = Wvt + (size_t)(panel - 2) * 128 * 256;
                         bias = bv + (panel - 2) * 128; Kd = 256; }

  f32x4 acc[8];
#pragma unroll
  for (int nt = 0; nt < 8; ++nt) acc[nt] = (f32x4){0.f, 0.f, 0.f, 0.f};

  const __bf16* arow_i = inpB + (size_t)(row0 + cl) * 256 + quad * 8;
  const __bf16* arow_f = featB + (size_t)(row0 + cl) * 256 + quad * 8;
  const __bf16* wrow   = Wt + (size_t)cl * Kd + quad * 8;

#pragma unroll 2
  for (int k0 = 0; k0 < 256; k0 += 32) {
    const bf16x8 af = *(const bf16x8*)(arow_i + k0);
#pragma unroll
    for (int nt = 0; nt < 8; ++nt) {
      const bf16x8 bfr = *(const bf16x8*)(wrow + (size_t)nt * 16 * Kd + k0);
      acc[nt] = __builtin_amdgcn_mfma_f32_16x16x32_bf16(af, bfr, acc[nt], 0, 0, 0);
    }
  }
  if (Kd == 512) {  // Q second half from feature
#pragma unroll 2
    for (int k0 = 0; k0 < 256; k0 += 32) {
      const bf16x8 af = *(const bf16x8*)(arow_f + k0);
#pragma unroll
      for (int nt = 0; nt < 8; ++nt) {
        const bf16x8 bfr = *(const bf16x8*)(wrow + (size_t)nt * 16 * Kd + 256 + k0);
        acc[nt] = __builtin_amdgcn_mfma_f32_16x16x32_bf16(af, bfr, acc[nt], 0, 0, 0);
      }
    }
  }

  if (panel < 2) {
    __bf16* dst = (panel == 0) ? qb : kb;
    const float scale = (panel == 0) ? INV_SQRT_K : 1.0f;
#pragma unroll
    for (int nt = 0; nt < 8; ++nt) {
      const float bs = bias[nt * 16 + cl];
#pragma unroll
      for (int r = 0; r < 4; ++r)
        dst[(size_t)(row0 + quad * 4 + r) * Kk + nt * 16 + cl] =
            (__bf16)((acc[nt][r] + bs) * scale);
    }
  } else {
    const int b = row0 >> 11, t0 = (row0 & (Tt - 1)) + quad * 4;
#pragma unroll
    for (int nt = 0; nt < 8; ++nt) {
      const float bs = bias[nt * 16 + cl];
      bf16x4 v4;
#pragma unroll
      for (int r = 0; r < 4; ++r) v4[r] = (__bf16)(acc[nt][r] + bs);
      *(bf16x4*)(vT + (size_t)(b * Vv + (panel - 2) * 128 + nt * 16 + cl) * Tt + t0) = v4;
    }
  }
}

// ---------------------------------------------------------------------------
// sexp: expS = exp(Q.K^T) for lower-triangular 128x128 blocks (packed slots),
//       + per-block column sums -> partialD[b][jt][i]. (unchanged)
// ---------------------------------------------------------------------------
__global__ __launch_bounds__(256) void sexp_kernel(
    const __bf16* __restrict__ qb, const __bf16* __restrict__ kb,
    __bf16* __restrict__ expS, float* __restrict__ partialD)
{
  const int b = blockIdx.y, l = blockIdx.x;
  int jt = 0, base = 0;
  while (base + jt + 1 <= l) { base += jt + 1; ++jt; }   // uniform, <=16 iters
  const int it = l - base;

  const int lane = threadIdx.x & 63, wave = threadIdx.x >> 6;
  const int cl = lane & 15, quad = lane >> 4;
  const int j0 = jt * 128 + (wave >> 1) * 64;
  const int i0 = it * 128 + (wave & 1) * 64;
  const size_t rowbase = (size_t)b * Tt;

  bf16x8 af[4][4], bfr[4][4];
  const __bf16* qrow = qb + (rowbase + j0 + cl) * Kk + quad * 8;
  const __bf16* krow = kb + (rowbase + i0 + cl) * Kk + quad * 8;
#pragma unroll
  for (int mt = 0; mt < 4; ++mt)
#pragma unroll
    for (int ks = 0; ks < 4; ++ks) af[mt][ks] = *(const bf16x8*)(qrow + mt * 16 * Kk + ks * 32);
#pragma unroll
  for (int nt = 0; nt < 4; ++nt)
#pragma unroll
    for (int ks = 0; ks < 4; ++ks) bfr[nt][ks] = *(const bf16x8*)(krow + nt * 16 * Kk + ks * 32);

  f32x4 acc[4][4];
#pragma unroll
  for (int mt = 0; mt < 4; ++mt)
#pragma unroll
    for (int nt = 0; nt < 4; ++nt) acc[mt][nt] = (f32x4){0.f, 0.f, 0.f, 0.f};

#pragma unroll
  for (int ks = 0; ks < 4; ++ks)
#pragma unroll
    for (int mt = 0; mt < 4; ++mt)
#pragma unroll
      for (int nt = 0; nt < 4; ++nt)
        acc[mt][nt] = __builtin_amdgcn_mfma_f32_16x16x32_bf16(af[mt][ks], bfr[nt][ks], acc[mt][nt], 0, 0, 0);

  // epilogue: exp, (diag mask), bf16 store to slot, column sums
  __bf16* slot = expS + ((size_t)(b * NTRI + l)) * (128 * 128);
  const bool diag = (it == jt);
  float cs[4] = {0.f, 0.f, 0.f, 0.f};
#pragma unroll
  for (int mt = 0; mt < 4; ++mt) {
    const int jl = (wave >> 1) * 64 + mt * 16 + quad * 4;
#pragma unroll
    for (int nt = 0; nt < 4; ++nt) {
      const int il = (wave & 1) * 64 + nt * 16 + cl;
#pragma unroll
      for (int r = 0; r < 4; ++r) {
        float p = __expf(acc[mt][nt][r]);
        if (diag && (i0 + nt * 16 + cl) > (j0 + mt * 16 + quad * 4 + r)) p = 0.f;
        const __bf16 pb = (__bf16)p;
        cs[nt] += (float)pb;            // sum the rounded value pass B will use
        slot[(size_t)(jl + r) * 128 + il] = pb;
      }
    }
  }
  __shared__ float lcs[4][64];
#pragma unroll
  for (int nt = 0; nt < 4; ++nt) {
    cs[nt] += __shfl_xor(cs[nt], 16);
    cs[nt] += __shfl_xor(cs[nt], 32);
  }
  if (quad == 0) {
#pragma unroll
    for (int nt = 0; nt < 4; ++nt) lcs[wave][nt * 16 + cl] = cs[nt];
  }
  __syncthreads();
  const int tid = threadIdx.x;
  if (tid < 128) {                      // block column c = tid
    const int w0 = (tid < 64) ? 0 : 1;  // waves {0,2} cols [0,64), {1,3} [64,128)
    const int lc = tid & 63;
    const float s = lcs[w0][lc] + lcs[w0 + 2][lc];
    partialD[((size_t)b * 16 + jt) * Tt + it * 128 + tid] = s;
  }
}

// ---------------------------------------------------------------------------
// dreduce: recipD[b][i] = 1 / sum_jt partialD[b][jt][i].  grid 64 x 256.
// ---------------------------------------------------------------------------
__global__ __launch_bounds__(256) void dreduce_kernel(
    const float* __restrict__ partialD, float* __restrict__ recipD)
{
  const int g = blockIdx.x * 256 + threadIdx.x;  // 0..16383
  const int b = g >> 11, i = g & (Tt - 1);
  float s = 0.f;
#pragma unroll
  for (int jt = 0; jt < 16; ++jt) s += partialD[((size_t)b * 16 + jt) * Tt + i];
  recipD[g] = 1.0f / s;
}

// ---------------------------------------------------------------------------
// vscale: vT[b][v][i] *= recipD[b][i]  (in place, bf16x8 per thread).
// ---------------------------------------------------------------------------
__global__ __launch_bounds__(256) void vscale_kernel(
    bf16x8* __restrict__ vT8, const float* __restrict__ recipD)
{
  const int g = blockIdx.x * 256 + threadIdx.x;      // bf16x8 unit
  const size_t e0 = (size_t)g * 8;
  const int i = (int)(e0 & (Tt - 1));
  const int b = (int)(e0 >> 19);                     // 256*2048 elems per batch
  bf16x8 v = vT8[g];
  const f32x4 r0 = *(const f32x4*)(recipD + (size_t)b * Tt + i);
  const f32x4 r1 = *(const f32x4*)(recipD + (size_t)b * Tt + i + 4);
#pragma unroll
  for (int t = 0; t < 4; ++t) v[t] = (__bf16)((float)v[t] * r0[t]);
#pragma unroll
  for (int t = 0; t < 4; ++t) v[4 + t] = (__bf16)((float)v[4 + t] * r1[t]);
  vT8[g] = v;
}

// ---------------------------------------------------------------------------
// pvgemm v2: out[:, :, 256:512] = expS @ vT_scaled, triangular k-loop.
//   grid (32 jt2 reversed, 2 vh, 8 b), block 256 = 4 waves.
//   Wave = 64j x 32v (acc[4][2] = 32 VGPRs). It-level ping-pong double
//   buffering: prefetch next 128-k block's 24 frags (A 16 + B 8) while
//   MFMAing current -> 24 loads in flight, latency overlapped.
//   __launch_bounds__(256,2): ~240 VGPR budget, 2 waves/SIMD; 512 blocks
//   -> 2 blocks/CU = 8 waves/CU.
// ---------------------------------------------------------------------------
#define LOAD_FRAGS(AF, BF, ar, br)                                            \
  {                                                                           \
    _Pragma("unroll") for (int mt = 0; mt < 4; ++mt)                          \
      _Pragma("unroll") for (int ks = 0; ks < 4; ++ks)                        \
        AF[mt][ks] = *(const bf16x8*)((ar) + mt * 2048 + ks * 32);            \
    _Pragma("unroll") for (int nt = 0; nt < 2; ++nt)                          \
      _Pragma("unroll") for (int ks = 0; ks < 4; ++ks)                        \
        BF[nt][ks] = *(const bf16x8*)((br) + (size_t)nt * 16 * Tt + ks * 32); \
  }
#define STAGE(AF, BF)                                                         \
  {                                                                           \
    _Pragma("unroll") for (int ks = 0; ks < 4; ++ks)                          \
      _Pragma("unroll") for (int mt = 0; mt < 4; ++mt)                        \
        _Pragma("unroll") for (int nt = 0; nt < 2; ++nt)                      \
          acc[mt][nt] = __builtin_amdgcn_mfma_f32_16x16x32_bf16(              \
              AF[mt][ks], BF[nt][ks], acc[mt][nt], 0, 0, 0);                  \
  }

__global__ __launch_bounds__(256, 2) void pvgemm_kernel(
    const __bf16* __restrict__ expS, const __bf16* __restrict__ vT,
    float* __restrict__ out)
{
  const int b = blockIdx.z, vh = blockIdx.y;
  const int jt2 = 31 - blockIdx.x;                   // longest first
  const int lane = threadIdx.x & 63, wave = threadIdx.x >> 6;
  const int cl = lane & 15, quad = lane >> 4;
  const int j0 = jt2 * 64;
  const int v0 = vh * 128 + wave * 32;
  const int jt = jt2 >> 1;                           // 128-slot row
  const int jl0 = (jt2 & 1) * 64;
  const int nits = jt + 1;
  const size_t slotrow = (size_t)(b * NTRI + (jt * (jt + 1)) / 2);  // + it

  f32x4 acc[4][2];
#pragma unroll
  for (int mt = 0; mt < 4; ++mt)
#pragma unroll
    for (int nt = 0; nt < 2; ++nt) acc[mt][nt] = (f32x4){0.f, 0.f, 0.f, 0.f};

  const __bf16* arow = expS + slotrow * 16384 + (size_t)(jl0 + cl) * 128 + quad * 8;
  const __bf16* brow = vT + ((size_t)b * Vv + v0 + cl) * Tt + quad * 8;

  bf16x8 afA[4][4], bfA[2][4], afB[4][4], bfB[2][4];
  LOAD_FRAGS(afA, bfA, arow, brow);
  for (int it = 0; it < nits; it += 2) {
    if (it + 1 < nits) LOAD_FRAGS(afB, bfB, arow + 16384, brow + 128);
    STAGE(afA, bfA);
    if (it + 1 < nits) {
      if (it + 2 < nits) LOAD_FRAGS(afA, bfA, arow + 2 * 16384, brow + 2 * 128);
      STAGE(afB, bfB);
    }
    arow += 2 * 16384; brow += 2 * 128;
  }

  float* orow = out + ((size_t)b * Tt + j0) * (size_t)(Cc + Vv) + Cc + v0;
#pragma unroll
  for (int mt = 0; mt < 4; ++mt)
#pragma unroll
    for (int nt = 0; nt < 2; ++nt)
#pragma unroll
      for (int r = 0; r < 4; ++r)
        orow[(size_t)(mt * 16 + quad * 4 + r) * (Cc + Vv) + nt * 16 + cl] = acc[mt][nt][r];
}

// ---------------------------------------------------------------------------
extern "C" void kernel_launch(void* const* d_in, const int* in_sizes, int n_in,
                              void* d_out, int out_size, void* d_ws, size_t ws_size,
                              hipStream_t stream) {
  const float* inp  = (const float*)d_in[0];
  const float* feat = (const float*)d_in[1];
  const float* Wq   = (const float*)d_in[2];
  const float* bq   = (const float*)d_in[3];
  const float* Wk   = (const float*)d_in[4];
  const float* bk   = (const float*)d_in[5];
  const float* Wv   = (const float*)d_in[6];
  const float* bv   = (const float*)d_in[7];
  float* out = (float*)d_out;

  // ws layout (~71 MB):
  //  inpB 8M | featB 8M | qb 4M | kb 4M | vT 8M | Wqt/Wkt/Wvt 320K |
  //  partialD 2M @33M | recipD 64K @35M | expS 34.8M @36M
  char* ws = (char*)d_ws;
  __bf16* inpB   = (__bf16*)(ws);
  __bf16* featB  = (__bf16*)(ws + (8u << 20));
  __bf16* qb     = (__bf16*)(ws + (16u << 20));
  __bf16* kb     = (__bf16*)(ws + (20u << 20));
  __bf16* vT     = (__bf16*)(ws + (24u << 20));
  __bf16* Wqt    = (__bf16*)(ws + (32u << 20));
  __bf16* Wkt    = (__bf16*)(ws + (32u << 20) + (128u << 10));
  __bf16* Wvt    = (__bf16*)(ws + (32u << 20) + (192u << 10));
  float*  partialD = (float*)(ws + (33u << 20));
  float*  recipD   = (float*)(ws + (35u << 20));
  __bf16* expS     = (__bf16*)(ws + (36u << 20));

  prep_kernel<<<dim3(BT * 64 / 256), 256, 0, stream>>>(
      (const float4*)inp, (const float4*)feat, (float4*)out,
      (bf16x4*)inpB, (bf16x4*)featB);
  wprep_kernel<<<dim3(640), 256, 0, stream>>>(Wq, Wk, Wv, Wqt, Wkt, Wvt);
  qkv_mfma_kernel<<<dim3(BT / 64, 4), 256, 0, stream>>>(
      inpB, featB, Wqt, Wkt, Wvt, bq, bk, bv, qb, kb, vT);
  sexp_kernel<<<dim3(NTRI, Bb), 256, 0, stream>>>(qb, kb, expS, partialD);
  dreduce_kernel<<<dim3(BT / 256), 256, 0, stream>>>(partialD, recipD);
  vscale_kernel<<<dim3(2048), 256, 0, stream>>>((bf16x8*)vT, recipD);
  pvgemm_kernel<<<dim3(Tt / 64, 2, Bb), 256, 0, stream>>>(expS, vT, out);
}

// Round 6
// 215.217 us; speedup vs baseline: 1.2245x; 1.2245x over previous
//
#include <hip/hip_runtime.h>
#include <hip/hip_bf16.h>
#include <cstdint>

// Problem constants
#define Bb  8
#define Tt  2048
#define Cc  256
#define FDd 256
#define Kk  128
#define Vv  256
#define BT  (Bb * Tt)
#define NTRI 136          // 16*17/2 lower-triangular 128x128 blocks per batch

#define INV_SQRT_K 0.08838834764831845f  // 1/sqrt(128)

typedef __bf16 bf16x8 __attribute__((ext_vector_type(8)));
typedef __bf16 bf16x4 __attribute__((ext_vector_type(4)));
typedef float  f32x4  __attribute__((ext_vector_type(4)));

// async global->LDS, 16B per lane. LDS dest = wave-uniform base + lane*16.
__device__ __forceinline__ void gload16(const void* g, void* l) {
  __builtin_amdgcn_global_load_lds(
      (const __attribute__((address_space(1))) void*)g,
      (__attribute__((address_space(3))) void*)l, 16, 0, 0);
}

// ---------------------------------------------------------------------------
// prep: out[:, :256] = inp (fp32 copy) + bf16 conversions of inp and feature.
// ---------------------------------------------------------------------------
__global__ __launch_bounds__(256) void prep_kernel(
    const float4* __restrict__ inp4, const float4* __restrict__ feat4,
    float4* __restrict__ out4, bf16x4* __restrict__ inpB4,
    bf16x4* __restrict__ featB4)
{
  const int g = blockIdx.x * 256 + threadIdx.x;   // 0 .. BT*64
  const int row = g >> 6, c = g & 63;
  const float4 x = inp4[g];
  out4[(size_t)row * 128 + c] = x;
  bf16x4 xb; xb[0] = (__bf16)x.x; xb[1] = (__bf16)x.y; xb[2] = (__bf16)x.z; xb[3] = (__bf16)x.w;
  inpB4[g] = xb;
  const float4 f = feat4[g];
  bf16x4 fb; fb[0] = (__bf16)f.x; fb[1] = (__bf16)f.y; fb[2] = (__bf16)f.z; fb[3] = (__bf16)f.w;
  featB4[g] = fb;
}

// ---------------------------------------------------------------------------
// wprep: transpose + bf16-convert weights.
// ---------------------------------------------------------------------------
__global__ __launch_bounds__(256) void wprep_kernel(
    const float* __restrict__ Wq, const float* __restrict__ Wk,
    const float* __restrict__ Wv, __bf16* __restrict__ Wqt,
    __bf16* __restrict__ Wkt, __bf16* __restrict__ Wvt)
{
  const int g = blockIdx.x * 256 + threadIdx.x;
  if (g < 65536) {                       // Wq: 512x128 -> Wqt 128x512
    const int n = g >> 9, k = g & 511;
    Wqt[g] = (__bf16)Wq[k * 128 + n];
  } else if (g < 98304) {                // Wk: 256x128 -> Wkt 128x256
    const int h = g - 65536;
    const int n = h >> 8, k = h & 255;
    Wkt[h] = (__bf16)Wk[k * 128 + n];
  } else {                               // Wv: 256x256 -> Wvt 256x256
    const int h = g - 98304;
    const int n = h >> 8, k = h & 255;
    Wvt[h] = (__bf16)Wv[k * 256 + n];
  }
}

// ---------------------------------------------------------------------------
// qkv via MFMA. grid (BT/64, 4), block 256 (4 waves x 16 rows). (unchanged)
// ---------------------------------------------------------------------------
__global__ __launch_bounds__(256) void qkv_mfma_kernel(
    const __bf16* __restrict__ inpB, const __bf16* __restrict__ featB,
    const __bf16* __restrict__ Wqt, const __bf16* __restrict__ Wkt,
    const __bf16* __restrict__ Wvt,
    const float* __restrict__ bq, const float* __restrict__ bk,
    const float* __restrict__ bv,
    __bf16* __restrict__ qb, __bf16* __restrict__ kb, __bf16* __restrict__ vT)
{
  const int panel = blockIdx.y;
  const int lane = threadIdx.x & 63, wave = threadIdx.x >> 6;
  const int cl = lane & 15, quad = lane >> 4;
  const int row0 = blockIdx.x * 64 + wave * 16;

  const __bf16* Wt; const float* bias; int Kd;
  if (panel == 0)      { Wt = Wqt; bias = bq; Kd = 512; }
  else if (panel == 1) { Wt = Wkt; bias = bk; Kd = 256; }
  else                 { Wt = Wvt + (size_t)(panel - 2) * 128 * 256;
                         bias = bv + (panel - 2) * 128; Kd = 256; }

  f32x4 acc[8];
#pragma unroll
  for (int nt = 0; nt < 8; ++nt) acc[nt] = (f32x4){0.f, 0.f, 0.f, 0.f};

  const __bf16* arow_i = inpB + (size_t)(row0 + cl) * 256 + quad * 8;
  const __bf16* arow_f = featB + (size_t)(row0 + cl) * 256 + quad * 8;
  const __bf16* wrow   = Wt + (size_t)cl * Kd + quad * 8;

#pragma unroll 2
  for (int k0 = 0; k0 < 256; k0 += 32) {
    const bf16x8 af = *(const bf16x8*)(arow_i + k0);
#pragma unroll
    for (int nt = 0; nt < 8; ++nt) {
      const bf16x8 bfr = *(const bf16x8*)(wrow + (size_t)nt * 16 * Kd + k0);
      acc[nt] = __builtin_amdgcn_mfma_f32_16x16x32_bf16(af, bfr, acc[nt], 0, 0, 0);
    }
  }
  if (Kd == 512) {  // Q second half from feature
#pragma unroll 2
    for (int k0 = 0; k0 < 256; k0 += 32) {
      const bf16x8 af = *(const bf16x8*)(arow_f + k0);
#pragma unroll
      for (int nt = 0; nt < 8; ++nt) {
        const bf16x8 bfr = *(const bf16x8*)(wrow + (size_t)nt * 16 * Kd + 256 + k0);
        acc[nt] = __builtin_amdgcn_mfma_f32_16x16x32_bf16(af, bfr, acc[nt], 0, 0, 0);
      }
    }
  }

  if (panel < 2) {
    __bf16* dst = (panel == 0) ? qb : kb;
    const float scale = (panel == 0) ? INV_SQRT_K : 1.0f;
#pragma unroll
    for (int nt = 0; nt < 8; ++nt) {
      const float bs = bias[nt * 16 + cl];
#pragma unroll
      for (int r = 0; r < 4; ++r)
        dst[(size_t)(row0 + quad * 4 + r) * Kk + nt * 16 + cl] =
            (__bf16)((acc[nt][r] + bs) * scale);
    }
  } else {
    const int b = row0 >> 11, t0 = (row0 & (Tt - 1)) + quad * 4;
#pragma unroll
    for (int nt = 0; nt < 8; ++nt) {
      const float bs = bias[nt * 16 + cl];
      bf16x4 v4;
#pragma unroll
      for (int r = 0; r < 4; ++r) v4[r] = (__bf16)(acc[nt][r] + bs);
      *(bf16x4*)(vT + (size_t)(b * Vv + (panel - 2) * 128 + nt * 16 + cl) * Tt + t0) = v4;
    }
  }
}

// ---------------------------------------------------------------------------
// sexp: expS = exp(Q.K^T) for lower-triangular 128x128 blocks (packed slots),
//       + per-block column sums -> partialD[b][jt][i]. (unchanged)
// ---------------------------------------------------------------------------
__global__ __launch_bounds__(256) void sexp_kernel(
    const __bf16* __restrict__ qb, const __bf16* __restrict__ kb,
    __bf16* __restrict__ expS, float* __restrict__ partialD)
{
  const int b = blockIdx.y, l = blockIdx.x;
  int jt = 0, base = 0;
  while (base + jt + 1 <= l) { base += jt + 1; ++jt; }   // uniform, <=16 iters
  const int it = l - base;

  const int lane = threadIdx.x & 63, wave = threadIdx.x >> 6;
  const int cl = lane & 15, quad = lane >> 4;
  const int j0 = jt * 128 + (wave >> 1) * 64;
  const int i0 = it * 128 + (wave & 1) * 64;
  const size_t rowbase = (size_t)b * Tt;

  bf16x8 af[4][4], bfr[4][4];
  const __bf16* qrow = qb + (rowbase + j0 + cl) * Kk + quad * 8;
  const __bf16* krow = kb + (rowbase + i0 + cl) * Kk + quad * 8;
#pragma unroll
  for (int mt = 0; mt < 4; ++mt)
#pragma unroll
    for (int ks = 0; ks < 4; ++ks) af[mt][ks] = *(const bf16x8*)(qrow + mt * 16 * Kk + ks * 32);
#pragma unroll
  for (int nt = 0; nt < 4; ++nt)
#pragma unroll
    for (int ks = 0; ks < 4; ++ks) bfr[nt][ks] = *(const bf16x8*)(krow + nt * 16 * Kk + ks * 32);

  f32x4 acc[4][4];
#pragma unroll
  for (int mt = 0; mt < 4; ++mt)
#pragma unroll
    for (int nt = 0; nt < 4; ++nt) acc[mt][nt] = (f32x4){0.f, 0.f, 0.f, 0.f};

#pragma unroll
  for (int ks = 0; ks < 4; ++ks)
#pragma unroll
    for (int mt = 0; mt < 4; ++mt)
#pragma unroll
      for (int nt = 0; nt < 4; ++nt)
        acc[mt][nt] = __builtin_amdgcn_mfma_f32_16x16x32_bf16(af[mt][ks], bfr[nt][ks], acc[mt][nt], 0, 0, 0);

  // epilogue: exp, (diag mask), bf16 store to slot, column sums
  __bf16* slot = expS + ((size_t)(b * NTRI + l)) * (128 * 128);
  const bool diag = (it == jt);
  float cs[4] = {0.f, 0.f, 0.f, 0.f};
#pragma unroll
  for (int mt = 0; mt < 4; ++mt) {
    const int jl = (wave >> 1) * 64 + mt * 16 + quad * 4;
#pragma unroll
    for (int nt = 0; nt < 4; ++nt) {
      const int il = (wave & 1) * 64 + nt * 16 + cl;
#pragma unroll
      for (int r = 0; r < 4; ++r) {
        float p = __expf(acc[mt][nt][r]);
        if (diag && (i0 + nt * 16 + cl) > (j0 + mt * 16 + quad * 4 + r)) p = 0.f;
        const __bf16 pb = (__bf16)p;
        cs[nt] += (float)pb;            // sum the rounded value pass B will use
        slot[(size_t)(jl + r) * 128 + il] = pb;
      }
    }
  }
  __shared__ float lcs[4][64];
#pragma unroll
  for (int nt = 0; nt < 4; ++nt) {
    cs[nt] += __shfl_xor(cs[nt], 16);
    cs[nt] += __shfl_xor(cs[nt], 32);
  }
  if (quad == 0) {
#pragma unroll
    for (int nt = 0; nt < 4; ++nt) lcs[wave][nt * 16 + cl] = cs[nt];
  }
  __syncthreads();
  const int tid = threadIdx.x;
  if (tid < 128) {                      // block column c = tid
    const int w0 = (tid < 64) ? 0 : 1;  // waves {0,2} cols [0,64), {1,3} [64,128)
    const int lc = tid & 63;
    const float s = lcs[w0][lc] + lcs[w0 + 2][lc];
    partialD[((size_t)b * 16 + jt) * Tt + it * 128 + tid] = s;
  }
}

// ---------------------------------------------------------------------------
// dreduce: recipD[b][i] = 1 / sum_jt partialD[b][jt][i].  grid 64 x 256.
// ---------------------------------------------------------------------------
__global__ __launch_bounds__(256) void dreduce_kernel(
    const float* __restrict__ partialD, float* __restrict__ recipD)
{
  const int g = blockIdx.x * 256 + threadIdx.x;  // 0..16383
  const int b = g >> 11, i = g & (Tt - 1);
  float s = 0.f;
#pragma unroll
  for (int jt = 0; jt < 16; ++jt) s += partialD[((size_t)b * 16 + jt) * Tt + i];
  recipD[g] = 1.0f / s;
}

// ---------------------------------------------------------------------------
// vscale: vT[b][v][i] *= recipD[b][i]  (in place, bf16x8 per thread).
// ---------------------------------------------------------------------------
__global__ __launch_bounds__(256) void vscale_kernel(
    bf16x8* __restrict__ vT8, const float* __restrict__ recipD)
{
  const int g = blockIdx.x * 256 + threadIdx.x;      // bf16x8 unit
  const size_t e0 = (size_t)g * 8;
  const int i = (int)(e0 & (Tt - 1));
  const int b = (int)(e0 >> 19);                     // 256*2048 elems per batch
  bf16x8 v = vT8[g];
  const f32x4 r0 = *(const f32x4*)(recipD + (size_t)b * Tt + i);
  const f32x4 r1 = *(const f32x4*)(recipD + (size_t)b * Tt + i + 4);
#pragma unroll
  for (int t = 0; t < 4; ++t) v[t] = (__bf16)((float)v[t] * r0[t]);
#pragma unroll
  for (int t = 0; t < 4; ++t) v[4 + t] = (__bf16)((float)v[4 + t] * r1[t]);
  vT8[g] = v;
}

// ---------------------------------------------------------------------------
// pvgemm v3 (m97-style): out[:, :, 256:512] = expS @ vT_scaled.
//   grid (32, 8): x -> (jt = 15 - x>>1 [longest first], nh = x&1), y = b.
//   Block = 128 j x 128 v, 4 waves in 2x2 (wave>>1 = m-half, wave&1 = n-half),
//   wave = 64x64 via 4x4 16x16 tiles. K-loop BK=64 over i in [0,(jt+1)*128).
//   A (expS) and B (vT) staged in LDS via global_load_lds width=16; the LDS
//   dest is lane-ordered (no padding possible), so bank conflicts are broken
//   by XOR-swizling the SOURCE chunk: LDS[row][c] = global chunk (c ^ row&7).
//   Frag ds_read_b128 then hits 8 distinct 4-bank groups x 2 lanes = free.
// ---------------------------------------------------------------------------
__global__ __launch_bounds__(256, 3) void pvgemm_kernel(
    const __bf16* __restrict__ expS, const __bf16* __restrict__ vT,
    float* __restrict__ out)
{
  __shared__ __bf16 Atile[128 * 64];   // [jlocal 128][k 64], chunks swizzled
  __shared__ __bf16 Btile[128 * 64];   // [vlocal 128][k 64], chunks swizzled
  const int b = blockIdx.y;
  const int jt = 15 - (blockIdx.x >> 1);
  const int nh = blockIdx.x & 1;
  const int lane = threadIdx.x & 63, wave = threadIdx.x >> 6;
  const int cl = lane & 15, quad = lane >> 4;
  const int jl0 = (wave >> 1) * 64;    // wave m-offset in tile
  const int vl0 = (wave & 1) * 64;     // wave n-offset in tile

  const int kblocks = (jt + 1) * 2;    // BK=64 steps
  const size_t slotbase = (size_t)(b * NTRI + (jt * (jt + 1)) / 2) * 16384;
  const __bf16* vbase = vT + ((size_t)b * Vv + nh * 128) * Tt;

  // staging: wave stages rows [32*wave, 32*wave+32) of both tiles, 4 instrs
  // each (8 rows/instr). lane L -> row +L>>3, source chunk (L&7)^(L>>3).
  const int lrow = lane >> 3;
  const int lchunk = ((lane & 7) ^ lrow) * 8;      // element offset of 16B chunk

  f32x4 acc[4][4];
#pragma unroll
  for (int mt = 0; mt < 4; ++mt)
#pragma unroll
    for (int nt = 0; nt < 4; ++nt) acc[mt][nt] = (f32x4){0.f, 0.f, 0.f, 0.f};

  for (int kb = 0; kb < kblocks; ++kb) {
    const int i0 = kb * 64;
    const __bf16* Ag = expS + slotbase + (size_t)(kb >> 1) * 16384 + (kb & 1) * 64;
    __syncthreads();                   // prior compute done before overwrite
#pragma unroll
    for (int t = 0; t < 4; ++t) {
      const int r0 = wave * 32 + t * 8;
      gload16(Ag + (size_t)(r0 + lrow) * 128 + lchunk, Atile + r0 * 64);
      gload16(vbase + (size_t)(r0 + lrow) * Tt + i0 + lchunk, Btile + r0 * 64);
    }
    __syncthreads();                   // waitcnt vmcnt(0) + barrier
#pragma unroll
    for (int ks = 0; ks < 2; ++ks) {
      bf16x8 af[4], bfr[4];
#pragma unroll
      for (int mt = 0; mt < 4; ++mt) {
        const int jlr = jl0 + mt * 16 + cl;
        af[mt] = *(const bf16x8*)(Atile + jlr * 64 + (((ks * 4 + quad) ^ (jlr & 7)) * 8));
      }
#pragma unroll
      for (int nt = 0; nt < 4; ++nt) {
        const int vlr = vl0 + nt * 16 + cl;
        bfr[nt] = *(const bf16x8*)(Btile + vlr * 64 + (((ks * 4 + quad) ^ (vlr & 7)) * 8));
      }
#pragma unroll
      for (int mt = 0; mt < 4; ++mt)
#pragma unroll
        for (int nt = 0; nt < 4; ++nt)
          acc[mt][nt] = __builtin_amdgcn_mfma_f32_16x16x32_bf16(af[mt], bfr[nt], acc[mt][nt], 0, 0, 0);
    }
  }

  float* orow = out + ((size_t)b * Tt + jt * 128 + jl0) * (size_t)(Cc + Vv)
              + Cc + nh * 128 + vl0;
#pragma unroll
  for (int mt = 0; mt < 4; ++mt)
#pragma unroll
    for (int nt = 0; nt < 4; ++nt)
#pragma unroll
      for (int r = 0; r < 4; ++r)
        orow[(size_t)(mt * 16 + quad * 4 + r) * (Cc + Vv) + nt * 16 + cl] = acc[mt][nt][r];
}

// ---------------------------------------------------------------------------
extern "C" void kernel_launch(void* const* d_in, const int* in_sizes, int n_in,
                              void* d_out, int out_size, void* d_ws, size_t ws_size,
                              hipStream_t stream) {
  const float* inp  = (const float*)d_in[0];
  const float* feat = (const float*)d_in[1];
  const float* Wq   = (const float*)d_in[2];
  const float* bq   = (const float*)d_in[3];
  const float* Wk   = (const float*)d_in[4];
  const float* bk   = (const float*)d_in[5];
  const float* Wv   = (const float*)d_in[6];
  const float* bv   = (const float*)d_in[7];
  float* out = (float*)d_out;

  // ws layout (~71 MB):
  //  inpB 8M | featB 8M | qb 4M | kb 4M | vT 8M | Wqt/Wkt/Wvt 320K |
  //  partialD 2M @33M | recipD 64K @35M | expS 34.8M @36M
  char* ws = (char*)d_ws;
  __bf16* inpB   = (__bf16*)(ws);
  __bf16* featB  = (__bf16*)(ws + (8u << 20));
  __bf16* qb     = (__bf16*)(ws + (16u << 20));
  __bf16* kb     = (__bf16*)(ws + (20u << 20));
  __bf16* vT     = (__bf16*)(ws + (24u << 20));
  __bf16* Wqt    = (__bf16*)(ws + (32u << 20));
  __bf16* Wkt    = (__bf16*)(ws + (32u << 20) + (128u << 10));
  __bf16* Wvt    = (__bf16*)(ws + (32u << 20) + (192u << 10));
  float*  partialD = (float*)(ws + (33u << 20));
  float*  recipD   = (float*)(ws + (35u << 20));
  __bf16* expS     = (__bf16*)(ws + (36u << 20));

  prep_kernel<<<dim3(BT * 64 / 256), 256, 0, stream>>>(
      (const float4*)inp, (const float4*)feat, (float4*)out,
      (bf16x4*)inpB, (bf16x4*)featB);
  wprep_kernel<<<dim3(640), 256, 0, stream>>>(Wq, Wk, Wv, Wqt, Wkt, Wvt);
  qkv_mfma_kernel<<<dim3(BT / 64, 4), 256, 0, stream>>>(
      inpB, featB, Wqt, Wkt, Wvt, bq, bk, bv, qb, kb, vT);
  sexp_kernel<<<dim3(NTRI, Bb), 256, 0, stream>>>(qb, kb, expS, partialD);
  dreduce_kernel<<<dim3(BT / 256), 256, 0, stream>>>(partialD, recipD);
  vscale_kernel<<<dim3(2048), 256, 0, stream>>>((bf16x8*)vT, recipD);
  pvgemm_kernel<<<dim3(32, Bb), 256, 0, stream>>>(expS, vT, out);
}

// Round 7
// 181.975 us; speedup vs baseline: 1.4482x; 1.1827x over previous
//
#include <hip/hip_runtime.h>
#include <hip/hip_bf16.h>
#include <cstdint>

// Problem constants
#define Bb  8
#define Tt  2048
#define Cc  256
#define FDd 256
#define Kk  128
#define Vv  256
#define BT  (Bb * Tt)
#define NTRI 136          // 16*17/2 lower-triangular 128x128 blocks per batch

#define INV_SQRT_K 0.08838834764831845f  // 1/sqrt(128)

typedef __bf16 bf16x8 __attribute__((ext_vector_type(8)));
typedef __bf16 bf16x4 __attribute__((ext_vector_type(4)));
typedef float  f32x4  __attribute__((ext_vector_type(4)));

// async global->LDS, 16B per lane. LDS dest = wave-uniform base + lane*16.
__device__ __forceinline__ void gload16(const void* g, void* l) {
  __builtin_amdgcn_global_load_lds(
      (const __attribute__((address_space(1))) void*)g,
      (__attribute__((address_space(3))) void*)l, 16, 0, 0);
}

// ---------------------------------------------------------------------------
// prep: out[:, :256] = inp (fp32 copy) + bf16 conversions of inp and feature.
// ---------------------------------------------------------------------------
__global__ __launch_bounds__(256) void prep_kernel(
    const float4* __restrict__ inp4, const float4* __restrict__ feat4,
    float4* __restrict__ out4, bf16x4* __restrict__ inpB4,
    bf16x4* __restrict__ featB4)
{
  const int g = blockIdx.x * 256 + threadIdx.x;   // 0 .. BT*64
  const int row = g >> 6, c = g & 63;
  const float4 x = inp4[g];
  out4[(size_t)row * 128 + c] = x;
  bf16x4 xb; xb[0] = (__bf16)x.x; xb[1] = (__bf16)x.y; xb[2] = (__bf16)x.z; xb[3] = (__bf16)x.w;
  inpB4[g] = xb;
  const float4 f = feat4[g];
  bf16x4 fb; fb[0] = (__bf16)f.x; fb[1] = (__bf16)f.y; fb[2] = (__bf16)f.z; fb[3] = (__bf16)f.w;
  featB4[g] = fb;
}

// ---------------------------------------------------------------------------
// wprep: transpose + bf16-convert weights. Wqt[n][k]=Wq[k][n] etc.
// ---------------------------------------------------------------------------
__global__ __launch_bounds__(256) void wprep_kernel(
    const float* __restrict__ Wq, const float* __restrict__ Wk,
    const float* __restrict__ Wv, __bf16* __restrict__ Wqt,
    __bf16* __restrict__ Wkt, __bf16* __restrict__ Wvt)
{
  const int g = blockIdx.x * 256 + threadIdx.x;
  if (g < 65536) {                       // Wq: 512x128 -> Wqt 128x512
    const int n = g >> 9, k = g & 511;
    Wqt[g] = (__bf16)Wq[k * 128 + n];
  } else if (g < 98304) {                // Wk: 256x128 -> Wkt 128x256
    const int h = g - 65536;
    const int n = h >> 8, k = h & 255;
    Wkt[h] = (__bf16)Wk[k * 128 + n];
  } else {                               // Wv: 256x256 -> Wvt 256x256
    const int h = g - 98304;
    const int n = h >> 8, k = h & 255;
    Wvt[h] = (__bf16)Wv[k * 256 + n];
  }
}

// ---------------------------------------------------------------------------
// qkv v2 (m97-style LDS tiles): one 128x128 output block per workgroup.
//   grid (128, 4): x = 128-row block of the 16384 activation rows; y = panel:
//     p0: Q (Kd=512: inpB k<256, featB k>=256), p1: K (Kd=256),
//     p2: V cols [0,128), p3: V cols [128,256)  -> vT[b][vcol][t]
//   Per BK=64 step: stage A (128x64 activations) + B (128x64 weight rows)
//   into LDS via global_load_lds w16 with XOR-swizzled source chunks
//   (same scheme as pvgemm: LDS[row][c] = global chunk c^(row&7));
//   4 waves in 2x2, each 64x64 = 32 MFMAs per step. Weights are L2-resident.
// ---------------------------------------------------------------------------
__global__ __launch_bounds__(256, 3) void qkv_mfma_kernel(
    const __bf16* __restrict__ inpB, const __bf16* __restrict__ featB,
    const __bf16* __restrict__ Wqt, const __bf16* __restrict__ Wkt,
    const __bf16* __restrict__ Wvt,
    const float* __restrict__ bq, const float* __restrict__ bk,
    const float* __restrict__ bv,
    __bf16* __restrict__ qb, __bf16* __restrict__ kb, __bf16* __restrict__ vT)
{
  __shared__ __bf16 Atile[128 * 64];
  __shared__ __bf16 Btile[128 * 64];
  const int panel = blockIdx.y;
  const int m0 = blockIdx.x * 128;
  const int lane = threadIdx.x & 63, wave = threadIdx.x >> 6;
  const int cl = lane & 15, quad = lane >> 4;
  const int jl0 = (wave >> 1) * 64;    // wave m-offset in tile
  const int vl0 = (wave & 1) * 64;     // wave n-offset in tile

  const __bf16* Wt; const float* bias; int kblocks;
  if (panel == 0)      { Wt = Wqt; bias = bq; kblocks = 8; }
  else if (panel == 1) { Wt = Wkt; bias = bk; kblocks = 4; }
  else                 { Wt = Wvt + (size_t)(panel - 2) * 128 * 256;
                         bias = bv + (panel - 2) * 128; kblocks = 4; }
  const int Kd = kblocks * 64;

  const int lrow = lane >> 3;
  const int lchunk = ((lane & 7) ^ lrow) * 8;      // element offset of 16B chunk

  f32x4 acc[4][4];
#pragma unroll
  for (int mt = 0; mt < 4; ++mt)
#pragma unroll
    for (int nt = 0; nt < 4; ++nt) acc[mt][nt] = (f32x4){0.f, 0.f, 0.f, 0.f};

  for (int kb = 0; kb < kblocks; ++kb) {
    // A source: Q switches to featB at kb>=4; others use inpB.
    const __bf16* Asrc = (panel == 0 && kb >= 4) ? featB : inpB;
    const int koff = (panel == 0 && kb >= 4) ? (kb - 4) * 64 : kb * 64;
    __syncthreads();                   // prior compute done before overwrite
#pragma unroll
    for (int t = 0; t < 4; ++t) {
      const int r0 = wave * 32 + t * 8;
      gload16(Asrc + (size_t)(m0 + r0 + lrow) * 256 + koff + lchunk, Atile + r0 * 64);
      gload16(Wt + (size_t)(r0 + lrow) * Kd + kb * 64 + lchunk, Btile + r0 * 64);
    }
    __syncthreads();                   // waitcnt vmcnt(0) + barrier
#pragma unroll
    for (int ks = 0; ks < 2; ++ks) {
      bf16x8 af[4], bfr[4];
#pragma unroll
      for (int mt = 0; mt < 4; ++mt) {
        const int jlr = jl0 + mt * 16 + cl;
        af[mt] = *(const bf16x8*)(Atile + jlr * 64 + (((ks * 4 + quad) ^ (jlr & 7)) * 8));
      }
#pragma unroll
      for (int nt = 0; nt < 4; ++nt) {
        const int vlr = vl0 + nt * 16 + cl;
        bfr[nt] = *(const bf16x8*)(Btile + vlr * 64 + (((ks * 4 + quad) ^ (vlr & 7)) * 8));
      }
#pragma unroll
      for (int mt = 0; mt < 4; ++mt)
#pragma unroll
        for (int nt = 0; nt < 4; ++nt)
          acc[mt][nt] = __builtin_amdgcn_mfma_f32_16x16x32_bf16(af[mt], bfr[nt], acc[mt][nt], 0, 0, 0);
    }
  }

  if (panel < 2) {
    __bf16* dst = (panel == 0) ? qb : kb;
    const float scale = (panel == 0) ? INV_SQRT_K : 1.0f;
#pragma unroll
    for (int mt = 0; mt < 4; ++mt) {
      const int row = m0 + jl0 + mt * 16 + quad * 4;
#pragma unroll
      for (int nt = 0; nt < 4; ++nt) {
        const int col = vl0 + nt * 16 + cl;
        const float bs = bias[col];
#pragma unroll
        for (int r = 0; r < 4; ++r)
          dst[(size_t)(row + r) * Kk + col] = (__bf16)((acc[mt][nt][r] + bs) * scale);
      }
    }
  } else {
    const int b = m0 >> 11;            // 128-row blocks never straddle a batch
#pragma unroll
    for (int mt = 0; mt < 4; ++mt) {
      const int t0 = (m0 & (Tt - 1)) + jl0 + mt * 16 + quad * 4;
#pragma unroll
      for (int nt = 0; nt < 4; ++nt) {
        const int vcol = (panel - 2) * 128 + vl0 + nt * 16 + cl;
        const float bs = bias[vl0 + nt * 16 + cl];
        bf16x4 v4;
#pragma unroll
        for (int r = 0; r < 4; ++r) v4[r] = (__bf16)(acc[mt][nt][r] + bs);
        *(bf16x4*)(vT + (size_t)(b * Vv + vcol) * Tt + t0) = v4;
      }
    }
  }
}

// ---------------------------------------------------------------------------
// sexp: expS = exp(Q.K^T) for lower-triangular 128x128 blocks (packed slots),
//       + per-block column sums -> partialD[b][jt][i]. (unchanged)
// ---------------------------------------------------------------------------
__global__ __launch_bounds__(256) void sexp_kernel(
    const __bf16* __restrict__ qb, const __bf16* __restrict__ kb,
    __bf16* __restrict__ expS, float* __restrict__ partialD)
{
  const int b = blockIdx.y, l = blockIdx.x;
  int jt = 0, base = 0;
  while (base + jt + 1 <= l) { base += jt + 1; ++jt; }   // uniform, <=16 iters
  const int it = l - base;

  const int lane = threadIdx.x & 63, wave = threadIdx.x >> 6;
  const int cl = lane & 15, quad = lane >> 4;
  const int j0 = jt * 128 + (wave >> 1) * 64;
  const int i0 = it * 128 + (wave & 1) * 64;
  const size_t rowbase = (size_t)b * Tt;

  bf16x8 af[4][4], bfr[4][4];
  const __bf16* qrow = qb + (rowbase + j0 + cl) * Kk + quad * 8;
  const __bf16* krow = kb + (rowbase + i0 + cl) * Kk + quad * 8;
#pragma unroll
  for (int mt = 0; mt < 4; ++mt)
#pragma unroll
    for (int ks = 0; ks < 4; ++ks) af[mt][ks] = *(const bf16x8*)(qrow + mt * 16 * Kk + ks * 32);
#pragma unroll
  for (int nt = 0; nt < 4; ++nt)
#pragma unroll
    for (int ks = 0; ks < 4; ++ks) bfr[nt][ks] = *(const bf16x8*)(krow + nt * 16 * Kk + ks * 32);

  f32x4 acc[4][4];
#pragma unroll
  for (int mt = 0; mt < 4; ++mt)
#pragma unroll
    for (int nt = 0; nt < 4; ++nt) acc[mt][nt] = (f32x4){0.f, 0.f, 0.f, 0.f};

#pragma unroll
  for (int ks = 0; ks < 4; ++ks)
#pragma unroll
    for (int mt = 0; mt < 4; ++mt)
#pragma unroll
      for (int nt = 0; nt < 4; ++nt)
        acc[mt][nt] = __builtin_amdgcn_mfma_f32_16x16x32_bf16(af[mt][ks], bfr[nt][ks], acc[mt][nt], 0, 0, 0);

  // epilogue: exp, (diag mask), bf16 store to slot, column sums
  __bf16* slot = expS + ((size_t)(b * NTRI + l)) * (128 * 128);
  const bool diag = (it == jt);
  float cs[4] = {0.f, 0.f, 0.f, 0.f};
#pragma unroll
  for (int mt = 0; mt < 4; ++mt) {
    const int jl = (wave >> 1) * 64 + mt * 16 + quad * 4;
#pragma unroll
    for (int nt = 0; nt < 4; ++nt) {
      const int il = (wave & 1) * 64 + nt * 16 + cl;
#pragma unroll
      for (int r = 0; r < 4; ++r) {
        float p = __expf(acc[mt][nt][r]);
        if (diag && (i0 + nt * 16 + cl) > (j0 + mt * 16 + quad * 4 + r)) p = 0.f;
        const __bf16 pb = (__bf16)p;
        cs[nt] += (float)pb;            // sum the rounded value pass B will use
        slot[(size_t)(jl + r) * 128 + il] = pb;
      }
    }
  }
  __shared__ float lcs[4][64];
#pragma unroll
  for (int nt = 0; nt < 4; ++nt) {
    cs[nt] += __shfl_xor(cs[nt], 16);
    cs[nt] += __shfl_xor(cs[nt], 32);
  }
  if (quad == 0) {
#pragma unroll
    for (int nt = 0; nt < 4; ++nt) lcs[wave][nt * 16 + cl] = cs[nt];
  }
  __syncthreads();
  const int tid = threadIdx.x;
  if (tid < 128) {                      // block column c = tid
    const int w0 = (tid < 64) ? 0 : 1;  // waves {0,2} cols [0,64), {1,3} [64,128)
    const int lc = tid & 63;
    const float s = lcs[w0][lc] + lcs[w0 + 2][lc];
    partialD[((size_t)b * 16 + jt) * Tt + it * 128 + tid] = s;
  }
}

// ---------------------------------------------------------------------------
// dreduce: recipD[b][i] = 1 / sum_jt partialD[b][jt][i].  grid 64 x 256.
// ---------------------------------------------------------------------------
__global__ __launch_bounds__(256) void dreduce_kernel(
    const float* __restrict__ partialD, float* __restrict__ recipD)
{
  const int g = blockIdx.x * 256 + threadIdx.x;  // 0..16383
  const int b = g >> 11, i = g & (Tt - 1);
  float s = 0.f;
#pragma unroll
  for (int jt = 0; jt < 16; ++jt) s += partialD[((size_t)b * 16 + jt) * Tt + i];
  recipD[g] = 1.0f / s;
}

// ---------------------------------------------------------------------------
// vscale: vT[b][v][i] *= recipD[b][i]  (in place, bf16x8 per thread).
// ---------------------------------------------------------------------------
__global__ __launch_bounds__(256) void vscale_kernel(
    bf16x8* __restrict__ vT8, const float* __restrict__ recipD)
{
  const int g = blockIdx.x * 256 + threadIdx.x;      // bf16x8 unit
  const size_t e0 = (size_t)g * 8;
  const int i = (int)(e0 & (Tt - 1));
  const int b = (int)(e0 >> 19);                     // 256*2048 elems per batch
  bf16x8 v = vT8[g];
  const f32x4 r0 = *(const f32x4*)(recipD + (size_t)b * Tt + i);
  const f32x4 r1 = *(const f32x4*)(recipD + (size_t)b * Tt + i + 4);
#pragma unroll
  for (int t = 0; t < 4; ++t) v[t] = (__bf16)((float)v[t] * r0[t]);
#pragma unroll
  for (int t = 0; t < 4; ++t) v[4 + t] = (__bf16)((float)v[4 + t] * r1[t]);
  vT8[g] = v;
}

// ---------------------------------------------------------------------------
// pvgemm v3 (m97-style): out[:, :, 256:512] = expS @ vT_scaled. (unchanged)
// ---------------------------------------------------------------------------
__global__ __launch_bounds__(256, 3) void pvgemm_kernel(
    const __bf16* __restrict__ expS, const __bf16* __restrict__ vT,
    float* __restrict__ out)
{
  __shared__ __bf16 Atile[128 * 64];   // [jlocal 128][k 64], chunks swizzled
  __shared__ __bf16 Btile[128 * 64];   // [vlocal 128][k 64], chunks swizzled
  const int b = blockIdx.y;
  const int jt = 15 - (blockIdx.x >> 1);
  const int nh = blockIdx.x & 1;
  const int lane = threadIdx.x & 63, wave = threadIdx.x >> 6;
  const int cl = lane & 15, quad = lane >> 4;
  const int jl0 = (wave >> 1) * 64;    // wave m-offset in tile
  const int vl0 = (wave & 1) * 64;     // wave n-offset in tile

  const int kblocks = (jt + 1) * 2;    // BK=64 steps
  const size_t slotbase = (size_t)(b * NTRI + (jt * (jt + 1)) / 2) * 16384;
  const __bf16* vbase = vT + ((size_t)b * Vv + nh * 128) * Tt;

  const int lrow = lane >> 3;
  const int lchunk = ((lane & 7) ^ lrow) * 8;      // element offset of 16B chunk

  f32x4 acc[4][4];
#pragma unroll
  for (int mt = 0; mt < 4; ++mt)
#pragma unroll
    for (int nt = 0; nt < 4; ++nt) acc[mt][nt] = (f32x4){0.f, 0.f, 0.f, 0.f};

  for (int kb = 0; kb < kblocks; ++kb) {
    const int i0 = kb * 64;
    const __bf16* Ag = expS + slotbase + (size_t)(kb >> 1) * 16384 + (kb & 1) * 64;
    __syncthreads();                   // prior compute done before overwrite
#pragma unroll
    for (int t = 0; t < 4; ++t) {
      const int r0 = wave * 32 + t * 8;
      gload16(Ag + (size_t)(r0 + lrow) * 128 + lchunk, Atile + r0 * 64);
      gload16(vbase + (size_t)(r0 + lrow) * Tt + i0 + lchunk, Btile + r0 * 64);
    }
    __syncthreads();                   // waitcnt vmcnt(0) + barrier
#pragma unroll
    for (int ks = 0; ks < 2; ++ks) {
      bf16x8 af[4], bfr[4];
#pragma unroll
      for (int mt = 0; mt < 4; ++mt) {
        const int jlr = jl0 + mt * 16 + cl;
        af[mt] = *(const bf16x8*)(Atile + jlr * 64 + (((ks * 4 + quad) ^ (jlr & 7)) * 8));
      }
#pragma unroll
      for (int nt = 0; nt < 4; ++nt) {
        const int vlr = vl0 + nt * 16 + cl;
        bfr[nt] = *(const bf16x8*)(Btile + vlr * 64 + (((ks * 4 + quad) ^ (vlr & 7)) * 8));
      }
#pragma unroll
      for (int mt = 0; mt < 4; ++mt)
#pragma unroll
        for (int nt = 0; nt < 4; ++nt)
          acc[mt][nt] = __builtin_amdgcn_mfma_f32_16x16x32_bf16(af[mt], bfr[nt], acc[mt][nt], 0, 0, 0);
    }
  }

  float* orow = out + ((size_t)b * Tt + jt * 128 + jl0) * (size_t)(Cc + Vv)
              + Cc + nh * 128 + vl0;
#pragma unroll
  for (int mt = 0; mt < 4; ++mt)
#pragma unroll
    for (int nt = 0; nt < 4; ++nt)
#pragma unroll
      for (int r = 0; r < 4; ++r)
        orow[(size_t)(mt * 16 + quad * 4 + r) * (Cc + Vv) + nt * 16 + cl] = acc[mt][nt][r];
}

// ---------------------------------------------------------------------------
extern "C" void kernel_launch(void* const* d_in, const int* in_sizes, int n_in,
                              void* d_out, int out_size, void* d_ws, size_t ws_size,
                              hipStream_t stream) {
  const float* inp  = (const float*)d_in[0];
  const float* feat = (const float*)d_in[1];
  const float* Wq   = (const float*)d_in[2];
  const float* bq   = (const float*)d_in[3];
  const float* Wk   = (const float*)d_in[4];
  const float* bk   = (const float*)d_in[5];
  const float* Wv   = (const float*)d_in[6];
  const float* bv   = (const float*)d_in[7];
  float* out = (float*)d_out;

  // ws layout (~71 MB):
  //  inpB 8M | featB 8M | qb 4M | kb 4M | vT 8M | Wqt/Wkt/Wvt 320K |
  //  partialD 2M @33M | recipD 64K @35M | expS 34.8M @36M
  char* ws = (char*)d_ws;
  __bf16* inpB   = (__bf16*)(ws);
  __bf16* featB  = (__bf16*)(ws + (8u << 20));
  __bf16* qb     = (__bf16*)(ws + (16u << 20));
  __bf16* kb     = (__bf16*)(ws + (20u << 20));
  __bf16* vT     = (__bf16*)(ws + (24u << 20));
  __bf16* Wqt    = (__bf16*)(ws + (32u << 20));
  __bf16* Wkt    = (__bf16*)(ws + (32u << 20) + (128u << 10));
  __bf16* Wvt    = (__bf16*)(ws + (32u << 20) + (192u << 10));
  float*  partialD = (float*)(ws + (33u << 20));
  float*  recipD   = (float*)(ws + (35u << 20));
  __bf16* expS     = (__bf16*)(ws + (36u << 20));

  prep_kernel<<<dim3(BT * 64 / 256), 256, 0, stream>>>(
      (const float4*)inp, (const float4*)feat, (float4*)out,
      (bf16x4*)inpB, (bf16x4*)featB);
  wprep_kernel<<<dim3(640), 256, 0, stream>>>(Wq, Wk, Wv, Wqt, Wkt, Wvt);
  qkv_mfma_kernel<<<dim3(BT / 128, 4), 256, 0, stream>>>(
      inpB, featB, Wqt, Wkt, Wvt, bq, bk, bv, qb, kb, vT);
  sexp_kernel<<<dim3(NTRI, Bb), 256, 0, stream>>>(qb, kb, expS, partialD);
  dreduce_kernel<<<dim3(BT / 256), 256, 0, stream>>>(partialD, recipD);
  vscale_kernel<<<dim3(2048), 256, 0, stream>>>((bf16x8*)vT, recipD);
  pvgemm_kernel<<<dim3(32, Bb), 256, 0, stream>>>(expS, vT, out);
}

// Round 8
// 174.398 us; speedup vs baseline: 1.5111x; 1.0434x over previous
//
#include <hip/hip_runtime.h>
#include <hip/hip_bf16.h>
#include <cstdint>

// Problem constants
#define Bb  8
#define Tt  2048
#define Cc  256
#define FDd 256
#define Kk  128
#define Vv  256
#define BT  (Bb * Tt)
#define NTRI 136          // 16*17/2 lower-triangular 128x128 blocks per batch

#define INV_SQRT_K 0.08838834764831845f  // 1/sqrt(128)

typedef __bf16 bf16x8 __attribute__((ext_vector_type(8)));
typedef __bf16 bf16x4 __attribute__((ext_vector_type(4)));
typedef float  f32x4  __attribute__((ext_vector_type(4)));

// async global->LDS, 16B per lane. LDS dest = wave-uniform base + lane*16.
__device__ __forceinline__ void gload16(const void* g, void* l) {
  __builtin_amdgcn_global_load_lds(
      (const __attribute__((address_space(1))) void*)g,
      (__attribute__((address_space(3))) void*)l, 16, 0, 0);
}

// ---------------------------------------------------------------------------
// prep: out[:, :256] = inp (fp32 copy) + bf16 conversions of inp and feature.
// ---------------------------------------------------------------------------
__global__ __launch_bounds__(256) void prep_kernel(
    const float4* __restrict__ inp4, const float4* __restrict__ feat4,
    float4* __restrict__ out4, bf16x4* __restrict__ inpB4,
    bf16x4* __restrict__ featB4)
{
  const int g = blockIdx.x * 256 + threadIdx.x;   // 0 .. BT*64
  const int row = g >> 6, c = g & 63;
  const float4 x = inp4[g];
  out4[(size_t)row * 128 + c] = x;
  bf16x4 xb; xb[0] = (__bf16)x.x; xb[1] = (__bf16)x.y; xb[2] = (__bf16)x.z; xb[3] = (__bf16)x.w;
  inpB4[g] = xb;
  const float4 f = feat4[g];
  bf16x4 fb; fb[0] = (__bf16)f.x; fb[1] = (__bf16)f.y; fb[2] = (__bf16)f.z; fb[3] = (__bf16)f.w;
  featB4[g] = fb;
}

// ---------------------------------------------------------------------------
// wprep: transpose + bf16-convert weights. Wqt[n][k]=Wq[k][n] etc.
// ---------------------------------------------------------------------------
__global__ __launch_bounds__(256) void wprep_kernel(
    const float* __restrict__ Wq, const float* __restrict__ Wk,
    const float* __restrict__ Wv, __bf16* __restrict__ Wqt,
    __bf16* __restrict__ Wkt, __bf16* __restrict__ Wvt)
{
  const int g = blockIdx.x * 256 + threadIdx.x;
  if (g < 65536) {                       // Wq: 512x128 -> Wqt 128x512
    const int n = g >> 9, k = g & 511;
    Wqt[g] = (__bf16)Wq[k * 128 + n];
  } else if (g < 98304) {                // Wk: 256x128 -> Wkt 128x256
    const int h = g - 65536;
    const int n = h >> 8, k = h & 255;
    Wkt[h] = (__bf16)Wk[k * 128 + n];
  } else {                               // Wv: 256x256 -> Wvt 256x256
    const int h = g - 98304;
    const int n = h >> 8, k = h & 255;
    Wvt[h] = (__bf16)Wv[k * 256 + n];
  }
}

// ---------------------------------------------------------------------------
// qkv v2 (m97-style LDS tiles): one 128x128 output block per workgroup.
//   (unchanged from round 7 — validated 46.6 -> ~13 us)
// ---------------------------------------------------------------------------
__global__ __launch_bounds__(256, 3) void qkv_mfma_kernel(
    const __bf16* __restrict__ inpB, const __bf16* __restrict__ featB,
    const __bf16* __restrict__ Wqt, const __bf16* __restrict__ Wkt,
    const __bf16* __restrict__ Wvt,
    const float* __restrict__ bq, const float* __restrict__ bk,
    const float* __restrict__ bv,
    __bf16* __restrict__ qb, __bf16* __restrict__ kb, __bf16* __restrict__ vT)
{
  __shared__ __bf16 Atile[128 * 64];
  __shared__ __bf16 Btile[128 * 64];
  const int panel = blockIdx.y;
  const int m0 = blockIdx.x * 128;
  const int lane = threadIdx.x & 63, wave = threadIdx.x >> 6;
  const int cl = lane & 15, quad = lane >> 4;
  const int jl0 = (wave >> 1) * 64;    // wave m-offset in tile
  const int vl0 = (wave & 1) * 64;     // wave n-offset in tile

  const __bf16* Wt; const float* bias; int kblocks;
  if (panel == 0)      { Wt = Wqt; bias = bq; kblocks = 8; }
  else if (panel == 1) { Wt = Wkt; bias = bk; kblocks = 4; }
  else                 { Wt = Wvt + (size_t)(panel - 2) * 128 * 256;
                         bias = bv + (panel - 2) * 128; kblocks = 4; }
  const int Kd = kblocks * 64;

  const int lrow = lane >> 3;
  const int lchunk = ((lane & 7) ^ lrow) * 8;      // element offset of 16B chunk

  f32x4 acc[4][4];
#pragma unroll
  for (int mt = 0; mt < 4; ++mt)
#pragma unroll
    for (int nt = 0; nt < 4; ++nt) acc[mt][nt] = (f32x4){0.f, 0.f, 0.f, 0.f};

  for (int kb = 0; kb < kblocks; ++kb) {
    const __bf16* Asrc = (panel == 0 && kb >= 4) ? featB : inpB;
    const int koff = (panel == 0 && kb >= 4) ? (kb - 4) * 64 : kb * 64;
    __syncthreads();                   // prior compute done before overwrite
#pragma unroll
    for (int t = 0; t < 4; ++t) {
      const int r0 = wave * 32 + t * 8;
      gload16(Asrc + (size_t)(m0 + r0 + lrow) * 256 + koff + lchunk, Atile + r0 * 64);
      gload16(Wt + (size_t)(r0 + lrow) * Kd + kb * 64 + lchunk, Btile + r0 * 64);
    }
    __syncthreads();                   // waitcnt vmcnt(0) + barrier
#pragma unroll
    for (int ks = 0; ks < 2; ++ks) {
      bf16x8 af[4], bfr[4];
#pragma unroll
      for (int mt = 0; mt < 4; ++mt) {
        const int jlr = jl0 + mt * 16 + cl;
        af[mt] = *(const bf16x8*)(Atile + jlr * 64 + (((ks * 4 + quad) ^ (jlr & 7)) * 8));
      }
#pragma unroll
      for (int nt = 0; nt < 4; ++nt) {
        const int vlr = vl0 + nt * 16 + cl;
        bfr[nt] = *(const bf16x8*)(Btile + vlr * 64 + (((ks * 4 + quad) ^ (vlr & 7)) * 8));
      }
#pragma unroll
      for (int mt = 0; mt < 4; ++mt)
#pragma unroll
        for (int nt = 0; nt < 4; ++nt)
          acc[mt][nt] = __builtin_amdgcn_mfma_f32_16x16x32_bf16(af[mt], bfr[nt], acc[mt][nt], 0, 0, 0);
    }
  }

  if (panel < 2) {
    __bf16* dst = (panel == 0) ? qb : kb;
    const float scale = (panel == 0) ? INV_SQRT_K : 1.0f;
#pragma unroll
    for (int mt = 0; mt < 4; ++mt) {
      const int row = m0 + jl0 + mt * 16 + quad * 4;
#pragma unroll
      for (int nt = 0; nt < 4; ++nt) {
        const int col = vl0 + nt * 16 + cl;
        const float bs = bias[col];
#pragma unroll
        for (int r = 0; r < 4; ++r)
          dst[(size_t)(row + r) * Kk + col] = (__bf16)((acc[mt][nt][r] + bs) * scale);
      }
    }
  } else {
    const int b = m0 >> 11;            // 128-row blocks never straddle a batch
#pragma unroll
    for (int mt = 0; mt < 4; ++mt) {
      const int t0 = (m0 & (Tt - 1)) + jl0 + mt * 16 + quad * 4;
#pragma unroll
      for (int nt = 0; nt < 4; ++nt) {
        const int vcol = (panel - 2) * 128 + vl0 + nt * 16 + cl;
        const float bs = bias[vl0 + nt * 16 + cl];
        bf16x4 v4;
#pragma unroll
        for (int r = 0; r < 4; ++r) v4[r] = (__bf16)(acc[mt][nt][r] + bs);
        *(bf16x4*)(vT + (size_t)(b * Vv + vcol) * Tt + t0) = v4;
      }
    }
  }
}

// ---------------------------------------------------------------------------
// sexp v2 (m97-style): expS = exp(Q.K^T) for lower-tri 128x128 blocks.
//   grid (136, 8), block 256 = 4 waves 2x2. K=128 -> single staging phase:
//   Qtile/Ktile 128x128 bf16 via gload16 + XOR chunk swizzle, 64 reg MFMAs.
//   Epilogue: masked exp as fp32 into the same 64 KB LDS (C-layout writes,
//   ~4-way conflicts), barrier, row-major readback -> bf16x8 -> 16 B
//   coalesced stores (8/lane instead of 64 scalar 2 B stores).
//   Column sums -> partialD[b][jt][i] (rounding-consistent with pass B).
// ---------------------------------------------------------------------------
__global__ __launch_bounds__(256, 2) void sexp_kernel(
    const __bf16* __restrict__ qb, const __bf16* __restrict__ kb,
    __bf16* __restrict__ expS, float* __restrict__ partialD)
{
  __shared__ __bf16 tiles[2 * 128 * 128];   // Qtile | Ktile; reused as fp32 P
  __shared__ float lcs[4][64];
  __bf16* Qtile = tiles;
  __bf16* Ktile = tiles + 128 * 128;
  float*  P     = (float*)tiles;            // 128x128 fp32 = 64 KB

  const int b = blockIdx.y, l = blockIdx.x;
  int jt = 0, base = 0;
  while (base + jt + 1 <= l) { base += jt + 1; ++jt; }   // uniform, <=16 iters
  const int it = l - base;

  const int lane = threadIdx.x & 63, wave = threadIdx.x >> 6;
  const int cl = lane & 15, quad = lane >> 4;
  const int jl0 = (wave >> 1) * 64;
  const int il0 = (wave & 1) * 64;
  const size_t rowbase = (size_t)b * Tt;

  // staging: 4 rows per gload16 (16 chunks/row); lane L -> row +L>>4,
  // slot L&15 holds source chunk (L&15)^(row&7).
  {
    const int srow = lane >> 4;          // 0..3
    const int cslot = lane & 15;
    const __bf16* qsrc = qb + (rowbase + jt * 128) * Kk;
    const __bf16* ksrc = kb + (rowbase + it * 128) * Kk;
#pragma unroll
    for (int t = 0; t < 8; ++t) {
      const int r0 = wave * 32 + t * 4;
      const int row = r0 + srow;
      const int cg = (cslot ^ (row & 7)) * 8;
      gload16(qsrc + (size_t)row * Kk + cg, Qtile + r0 * 128);
      gload16(ksrc + (size_t)row * Kk + cg, Ktile + r0 * 128);
    }
  }
  __syncthreads();

  f32x4 acc[4][4];
#pragma unroll
  for (int mt = 0; mt < 4; ++mt)
#pragma unroll
    for (int nt = 0; nt < 4; ++nt) acc[mt][nt] = (f32x4){0.f, 0.f, 0.f, 0.f};

#pragma unroll
  for (int s = 0; s < 4; ++s) {
    bf16x8 af[4], bfr[4];
#pragma unroll
    for (int mt = 0; mt < 4; ++mt) {
      const int jlr = jl0 + mt * 16 + cl;
      af[mt] = *(const bf16x8*)(Qtile + jlr * 128 + (((s * 4 + quad) ^ (jlr & 7)) * 8));
    }
#pragma unroll
    for (int nt = 0; nt < 4; ++nt) {
      const int ilr = il0 + nt * 16 + cl;
      bfr[nt] = *(const bf16x8*)(Ktile + ilr * 128 + (((s * 4 + quad) ^ (ilr & 7)) * 8));
    }
#pragma unroll
    for (int mt = 0; mt < 4; ++mt)
#pragma unroll
      for (int nt = 0; nt < 4; ++nt)
        acc[mt][nt] = __builtin_amdgcn_mfma_f32_16x16x32_bf16(af[mt], bfr[nt], acc[mt][nt], 0, 0, 0);
  }
  __syncthreads();                       // tiles free -> reuse as P

  // masked exp -> fp32 P (C-layout writes) + column sums of rounded values
  const bool diag = (it == jt);
  float cs[4] = {0.f, 0.f, 0.f, 0.f};
#pragma unroll
  for (int mt = 0; mt < 4; ++mt) {
    const int jl = jl0 + mt * 16 + quad * 4;
#pragma unroll
    for (int nt = 0; nt < 4; ++nt) {
      const int il = il0 + nt * 16 + cl;
#pragma unroll
      for (int r = 0; r < 4; ++r) {
        float p = __expf(acc[mt][nt][r]);
        if (diag && il > (jl + r)) p = 0.f;   // mask i > j (same-tile coords)
        cs[nt] += (float)(__bf16)p;           // what pass B will consume
        P[(jl + r) * 128 + il] = p;
      }
    }
  }
#pragma unroll
  for (int nt = 0; nt < 4; ++nt) {
    cs[nt] += __shfl_xor(cs[nt], 16);
    cs[nt] += __shfl_xor(cs[nt], 32);
  }
  if (quad == 0) {
#pragma unroll
    for (int nt = 0; nt < 4; ++nt) lcs[wave][nt * 16 + cl] = cs[nt];
  }
  __syncthreads();

  // coalesced bf16 store: 4 rows per pass, lane L -> row +L>>4, 8 elems.
  __bf16* slot = expS + ((size_t)(b * NTRI + l)) * (128 * 128);
  {
    const int srow = lane >> 4;
    const int c0 = (lane & 15) * 8;
#pragma unroll
    for (int t = 0; t < 8; ++t) {
      const int row = wave * 32 + t * 4 + srow;
      const f32x4 p0 = *(const f32x4*)(P + row * 128 + c0);
      const f32x4 p1 = *(const f32x4*)(P + row * 128 + c0 + 4);
      bf16x8 pb;
#pragma unroll
      for (int u = 0; u < 4; ++u) { pb[u] = (__bf16)p0[u]; pb[4 + u] = (__bf16)p1[u]; }
      *(bf16x8*)(slot + (size_t)row * 128 + c0) = pb;
    }
  }

  const int tid = threadIdx.x;
  if (tid < 128) {                      // block column c = tid
    const int w0 = (tid < 64) ? 0 : 1;  // waves {0,2} cols [0,64), {1,3} [64,128)
    const int lc = tid & 63;
    const float s = lcs[w0][lc] + lcs[w0 + 2][lc];
    partialD[((size_t)b * 16 + jt) * Tt + it * 128 + tid] = s;
  }
}

// ---------------------------------------------------------------------------
// dreduce: recipD[b][i] = 1 / sum_jt partialD[b][jt][i].  grid 64 x 256.
// ---------------------------------------------------------------------------
__global__ __launch_bounds__(256) void dreduce_kernel(
    const float* __restrict__ partialD, float* __restrict__ recipD)
{
  const int g = blockIdx.x * 256 + threadIdx.x;  // 0..16383
  const int b = g >> 11, i = g & (Tt - 1);
  float s = 0.f;
#pragma unroll
  for (int jt = 0; jt < 16; ++jt) s += partialD[((size_t)b * 16 + jt) * Tt + i];
  recipD[g] = 1.0f / s;
}

// ---------------------------------------------------------------------------
// vscale: vT[b][v][i] *= recipD[b][i]  (in place, bf16x8 per thread).
// ---------------------------------------------------------------------------
__global__ __launch_bounds__(256) void vscale_kernel(
    bf16x8* __restrict__ vT8, const float* __restrict__ recipD)
{
  const int g = blockIdx.x * 256 + threadIdx.x;      // bf16x8 unit
  const size_t e0 = (size_t)g * 8;
  const int i = (int)(e0 & (Tt - 1));
  const int b = (int)(e0 >> 19);                     // 256*2048 elems per batch
  bf16x8 v = vT8[g];
  const f32x4 r0 = *(const f32x4*)(recipD + (size_t)b * Tt + i);
  const f32x4 r1 = *(const f32x4*)(recipD + (size_t)b * Tt + i + 4);
#pragma unroll
  for (int t = 0; t < 4; ++t) v[t] = (__bf16)((float)v[t] * r0[t]);
#pragma unroll
  for (int t = 0; t < 4; ++t) v[4 + t] = (__bf16)((float)v[4 + t] * r1[t]);
  vT8[g] = v;
}

// ---------------------------------------------------------------------------
// pvgemm v3 (m97-style): out[:, :, 256:512] = expS @ vT_scaled. (unchanged)
// ---------------------------------------------------------------------------
__global__ __launch_bounds__(256, 3) void pvgemm_kernel(
    const __bf16* __restrict__ expS, const __bf16* __restrict__ vT,
    float* __restrict__ out)
{
  __shared__ __bf16 Atile[128 * 64];   // [jlocal 128][k 64], chunks swizzled
  __shared__ __bf16 Btile[128 * 64];   // [vlocal 128][k 64], chunks swizzled
  const int b = blockIdx.y;
  const int jt = 15 - (blockIdx.x >> 1);
  const int nh = blockIdx.x & 1;
  const int lane = threadIdx.x & 63, wave = threadIdx.x >> 6;
  const int cl = lane & 15, quad = lane >> 4;
  const int jl0 = (wave >> 1) * 64;    // wave m-offset in tile
  const int vl0 = (wave & 1) * 64;     // wave n-offset in tile

  const int kblocks = (jt + 1) * 2;    // BK=64 steps
  const size_t slotbase = (size_t)(b * NTRI + (jt * (jt + 1)) / 2) * 16384;
  const __bf16* vbase = vT + ((size_t)b * Vv + nh * 128) * Tt;

  const int lrow = lane >> 3;
  const int lchunk = ((lane & 7) ^ lrow) * 8;      // element offset of 16B chunk

  f32x4 acc[4][4];
#pragma unroll
  for (int mt = 0; mt < 4; ++mt)
#pragma unroll
    for (int nt = 0; nt < 4; ++nt) acc[mt][nt] = (f32x4){0.f, 0.f, 0.f, 0.f};

  for (int kb = 0; kb < kblocks; ++kb) {
    const int i0 = kb * 64;
    const __bf16* Ag = expS + slotbase + (size_t)(kb >> 1) * 16384 + (kb & 1) * 64;
    __syncthreads();                   // prior compute done before overwrite
#pragma unroll
    for (int t = 0; t < 4; ++t) {
      const int r0 = wave * 32 + t * 8;
      gload16(Ag + (size_t)(r0 + lrow) * 128 + lchunk, Atile + r0 * 64);
      gload16(vbase + (size_t)(r0 + lrow) * Tt + i0 + lchunk, Btile + r0 * 64);
    }
    __syncthreads();                   // waitcnt vmcnt(0) + barrier
#pragma unroll
    for (int ks = 0; ks < 2; ++ks) {
      bf16x8 af[4], bfr[4];
#pragma unroll
      for (int mt = 0; mt < 4; ++mt) {
        const int jlr = jl0 + mt * 16 + cl;
        af[mt] = *(const bf16x8*)(Atile + jlr * 64 + (((ks * 4 + quad) ^ (jlr & 7)) * 8));
      }
#pragma unroll
      for (int nt = 0; nt < 4; ++nt) {
        const int vlr = vl0 + nt * 16 + cl;
        bfr[nt] = *(const bf16x8*)(Btile + vlr * 64 + (((ks * 4 + quad) ^ (vlr & 7)) * 8));
      }
#pragma unroll
      for (int mt = 0; mt < 4; ++mt)
#pragma unroll
        for (int nt = 0; nt < 4; ++nt)
          acc[mt][nt] = __builtin_amdgcn_mfma_f32_16x16x32_bf16(af[mt], bfr[nt], acc[mt][nt], 0, 0, 0);
    }
  }

  float* orow = out + ((size_t)b * Tt + jt * 128 + jl0) * (size_t)(Cc + Vv)
              + Cc + nh * 128 + vl0;
#pragma unroll
  for (int mt = 0; mt < 4; ++mt)
#pragma unroll
    for (int nt = 0; nt < 4; ++nt)
#pragma unroll
      for (int r = 0; r < 4; ++r)
        orow[(size_t)(mt * 16 + quad * 4 + r) * (Cc + Vv) + nt * 16 + cl] = acc[mt][nt][r];
}

// ---------------------------------------------------------------------------
extern "C" void kernel_launch(void* const* d_in, const int* in_sizes, int n_in,
                              void* d_out, int out_size, void* d_ws, size_t ws_size,
                              hipStream_t stream) {
  const float* inp  = (const float*)d_in[0];
  const float* feat = (const float*)d_in[1];
  const float* Wq   = (const float*)d_in[2];
  const float* bq   = (const float*)d_in[3];
  const float* Wk   = (const float*)d_in[4];
  const float* bk   = (const float*)d_in[5];
  const float* Wv   = (const float*)d_in[6];
  const float* bv   = (const float*)d_in[7];
  float* out = (float*)d_out;

  // ws layout (~71 MB):
  //  inpB 8M | featB 8M | qb 4M | kb 4M | vT 8M | Wqt/Wkt/Wvt 320K |
  //  partialD 2M @33M | recipD 64K @35M | expS 34.8M @36M
  char* ws = (char*)d_ws;
  __bf16* inpB   = (__bf16*)(ws);
  __bf16* featB  = (__bf16*)(ws + (8u << 20));
  __bf16* qb     = (__bf16*)(ws + (16u << 20));
  __bf16* kb     = (__bf16*)(ws + (20u << 20));
  __bf16* vT     = (__bf16*)(ws + (24u << 20));
  __bf16* Wqt    = (__bf16*)(ws + (32u << 20));
  __bf16* Wkt    = (__bf16*)(ws + (32u << 20) + (128u << 10));
  __bf16* Wvt    = (__bf16*)(ws + (32u << 20) + (192u << 10));
  float*  partialD = (float*)(ws + (33u << 20));
  float*  recipD   = (float*)(ws + (35u << 20));
  __bf16* expS     = (__bf16*)(ws + (36u << 20));

  prep_kernel<<<dim3(BT * 64 / 256), 256, 0, stream>>>(
      (const float4*)inp, (const float4*)feat, (float4*)out,
      (bf16x4*)inpB, (bf16x4*)featB);
  wprep_kernel<<<dim3(640), 256, 0, stream>>>(Wq, Wk, Wv, Wqt, Wkt, Wvt);
  qkv_mfma_kernel<<<dim3(BT / 128, 4), 256, 0, stream>>>(
      inpB, featB, Wqt, Wkt, Wvt, bq, bk, bv, qb, kb, vT);
  sexp_kernel<<<dim3(NTRI, Bb), 256, 0, stream>>>(qb, kb, expS, partialD);
  dreduce_kernel<<<dim3(BT / 256), 256, 0, stream>>>(partialD, recipD);
  vscale_kernel<<<dim3(2048), 256, 0, stream>>>((bf16x8*)vT, recipD);
  pvgemm_kernel<<<dim3(32, Bb), 256, 0, stream>>>(expS, vT, out);
}